// Round 10
// baseline (405.878 us; speedup 1.0000x reference)
//
#include <hip/hip_runtime.h>
#include <hip/hip_bf16.h>

// Problem constants
#define V_   16000
#define D_   1024
#define H_   1024
#define E_   8
#define C_   16
#define B_   64
#define S_   512
#define GH_  256
#define NPAIR 128   // B_ * K(=2)

typedef short  bf16x8 __attribute__((ext_vector_type(8)));
typedef ushort u16x8  __attribute__((ext_vector_type(8)));
typedef float  f32x4  __attribute__((ext_vector_type(4)));

static __device__ __forceinline__ ushort f2bf(float f) {
  union { float f; unsigned u; } un; un.f = f;
  unsigned u = un.u;
  return (ushort)((u + 0x7FFFu + ((u >> 16) & 1u)) >> 16);  // RNE
}

static __device__ __forceinline__ unsigned pk2(float lo, float hi) {
  __hip_bfloat162 h = __float22bfloat162_rn(make_float2(lo, hi));  // v_cvt_pk_bf16_f32
  unsigned r; __builtin_memcpy(&r, &h, sizeof(r)); return r;
}

static __device__ __forceinline__ uint4 cvt8(f32x4 a, f32x4 b) {
  uint4 w;
  w.x = pk2(a[0], a[1]); w.y = pk2(a[2], a[3]);
  w.z = pk2(b[0], b[1]); w.w = pk2(b[2], b[3]);
  return w;
}

static __device__ __forceinline__ void gload_lds16(const void* g, void* l) {
  __builtin_amdgcn_global_load_lds((const __attribute__((address_space(1))) void*)g,
                                   (__attribute__((address_space(3))) void*)l, 16, 0, 0);
}

// Shared tile format for A and B operands: 16 KB K-tile = [row(128)][64 k] bf16,
// swizzled: ushort idx = row*64 + (kcol ^ ((row&7)<<3)), kcol in 8-ushort groups.
// global_load_lds copies tiles LINEARLY; ds_read_b128 applies the XOR -> conflict-free.

// ---------------------------------------------------------------------------
// Kernel 0 (fused prep):
//  blocks [0,2048): repack exp_w1 (E,D,H) f32 -> w1t bf16 tiles
//     [e][mtile(8)][kb(16)] each 128h x 64k swizzled as above.
//  blocks [2048,2560): partial pooling partial[b][sb8][d]
__global__ void prep_kernel(const float* __restrict__ w1, ushort* __restrict__ w1t,
                            const int* __restrict__ x, const float* __restrict__ emb,
                            float* __restrict__ partial) {
  __shared__ float tile[64][65];
  const int id = blockIdx.x;
  if (id < 2048) {
    const int e = id >> 8, rem = id & 255;
    const int dtile = rem & 15, htile = rem >> 4;   // dtile = kb, htile = 64-h group
    const int d0 = dtile * 64, h0 = htile * 64;
    const float* src = w1 + (size_t)e * D_ * H_;
    for (int i = threadIdx.x; i < 64 * 64; i += 256) {
      int r = i >> 6, c = i & 63;                 // r: k-local, c: h-local
      tile[r][c] = src[(size_t)(d0 + r) * H_ + h0 + c];
    }
    __syncthreads();
    const int mt = htile >> 1;
    const int rbase = (htile & 1) * 64;
    for (int i = threadIdx.x; i < 512; i += 256) {
      int r64 = i >> 3, kg = i & 7;
      u16x8 v;
      #pragma unroll
      for (int j = 0; j < 8; ++j) v[j] = f2bf(tile[kg * 8 + j][r64]);
      const int r = rbase + r64;
      size_t off = ((size_t)((e * 8 + mt) * 16 + dtile)) * 8192
                   + r * 64 + ((kg * 8) ^ ((r & 7) << 3));
      *reinterpret_cast<u16x8*>(w1t + off) = v;
    }
  } else {
    const int pid = id - 2048;
    const int b = pid >> 3, sb = pid & 7, t = threadIdx.x;
    const int* xr = x + b * S_ + sb * 64;
    float4 acc = make_float4(0.f, 0.f, 0.f, 0.f);
    #pragma unroll 4
    for (int s = 0; s < 64; ++s) {
      const float4* row = reinterpret_cast<const float4*>(emb + (size_t)xr[s] * D_);
      float4 v = row[t];
      acc.x += v.x; acc.y += v.y; acc.z += v.z; acc.w += v.w;
    }
    reinterpret_cast<float4*>(partial + ((size_t)b * 8 + sb) * D_)[t] = acc;
  }
}

// ---------------------------------------------------------------------------
// Kernel 1: reduce partials + gating MLP + top-2 + renormalize (all f32)
__global__ void gate_kernel(const float* __restrict__ partial,
                            const float* __restrict__ gw1, const float* __restrict__ gb1,
                            const float* __restrict__ gw2, const float* __restrict__ gb2,
                            int* __restrict__ ridx, float* __restrict__ rwgt) {
  const int b = blockIdx.x, j = threadIdx.x;
  __shared__ float pl[D_];
  __shared__ float hid[GH_];
  __shared__ float logits[E_];
  for (int d = j; d < D_; d += 256) {
    float s = 0.f;
    #pragma unroll
    for (int sb = 0; sb < 8; ++sb) s += partial[((size_t)b * 8 + sb) * D_ + d];
    pl[d] = s * (1.f / (float)S_);
  }
  __syncthreads();
  float acc = gb1[j];
  for (int d = 0; d < D_; ++d) acc += pl[d] * gw1[d * GH_ + j];
  hid[j] = fmaxf(acc, 0.f);
  __syncthreads();
  if (j < E_) {
    float l = gb2[j];
    for (int i = 0; i < GH_; ++i) l += hid[i] * gw2[i * E_ + j];
    logits[j] = l;
  }
  __syncthreads();
  if (j == 0) {
    int i0 = 0; float v0 = logits[0];
    for (int i = 1; i < E_; ++i) if (logits[i] > v0) { v0 = logits[i]; i0 = i; }
    int i1 = -1; float v1 = -3.0e38f;
    for (int i = 0; i < E_; ++i) {
      if (i == i0) continue;
      if (logits[i] > v1) { v1 = logits[i]; i1 = i; }
    }
    float r1 = expf(v1 - v0);
    float norm = 1.f + r1;
    ridx[b * 2 + 0] = i0;         ridx[b * 2 + 1] = i1;
    rwgt[b * 2 + 0] = 1.f / norm; rwgt[b * 2 + 1] = r1 / norm;
  }
}

// ---------------------------------------------------------------------------
// Kernel 2: stable counting-rank sort of pairs by expert id. 1 block, 128 thr.
__global__ void sort_pairs_kernel(const int* __restrict__ ridx, int* __restrict__ order) {
  __shared__ int se[NPAIR];
  const int t = threadIdx.x;
  se[t] = ridx[t];
  __syncthreads();
  const int e = se[t];
  int rank = 0;
  for (int j = 0; j < NPAIR; ++j) {
    const int ej = se[j];
    rank += (ej < e || (ej == e && j < t)) ? 1 : 0;
  }
  order[rank] = t;
}

// ---------------------------------------------------------------------------
// Kernel 3: gather + f32->bf16 convert of routed tokens into pre-swizzled
//   B tiles: xbf[(ss*4+sb4)*16 + kb] = 16 KB tile, 128 tokens x 64 k.
// grid (128 ss, 4 sb4), block 256: thread = (token row r = t>>1, d-half)
__global__ __launch_bounds__(256) void gatherconv_kernel(
    const int* __restrict__ x, const float* __restrict__ exp_emb,
    const int* __restrict__ ridx, const int* __restrict__ order,
    ushort* __restrict__ xbf) {
  const int ss = blockIdx.x, sb4 = blockIdx.y;
  const int pr = order[ss], e = ridx[pr], b = pr >> 1;
  const int t = threadIdx.x;
  const int r = t >> 1, dh = t & 1;
  const int tok = x[b * S_ + sb4 * 128 + r];
  const float* src = exp_emb + ((size_t)e * V_ + tok) * D_ + dh * 512;
  ushort* dstTile = xbf + ((size_t)(ss * 4 + sb4) * 16) * 8192;
  const int swz = (r & 7) << 3;
  #pragma unroll
  for (int q = 0; q < 8; ++q) {
    const int kb = dh * 8 + q;
    const float* s0 = src + q * 64;
    f32x4 v[16];
    #pragma unroll
    for (int i = 0; i < 16; ++i) v[i] = *reinterpret_cast<const f32x4*>(s0 + i * 4);
    ushort* dst = dstTile + (size_t)kb * 8192 + r * 64;
    #pragma unroll
    for (int kg = 0; kg < 8; ++kg) {
      uint4 w = cvt8(v[2 * kg], v[2 * kg + 1]);
      *reinterpret_cast<uint4*>(dst + ((kg * 8) ^ swz)) = w;
    }
  }
}

// ---------------------------------------------------------------------------
// Kernel 4: pure bf16 GEMM (m97 structure) + fused bias/ReLU/s-reduce.
//   Block = 128h x 128s tile of one (expert, pair-slot) pair; K = 1024.
//   4 waves (wave 64x64, 4x4 frags); 32 KB single-buffered LDS;
//   8x global_load_lds per K-step; 2 barriers per K-step.
//   XCD-bijective swizzle: XCD x gets ids [512x, 512x+512) = ntiles [64x,+64)
//   (same-expert, A L2-resident); 8 consecutive ids share one B tile.
// grid(4096), block 256.
__global__ __launch_bounds__(256, 4) void gemm_kernel(
    const ushort* __restrict__ w1t, const ushort* __restrict__ xbf,
    const float* __restrict__ exp_b1,
    const int* __restrict__ ridx, const int* __restrict__ order,
    float* __restrict__ ppart) {
  __shared__ __align__(16) ushort lA[8192];   // 16 KB: 128h x 64k swizzled
  __shared__ __align__(16) ushort lB[8192];   // 16 KB: 128s x 64k swizzled
  __shared__ float sred[2][128];

  const int g  = blockIdx.x;
  const int id = (g & 7) * 512 + (g >> 3);    // bijective (4096 % 8 == 0)
  const int n  = id >> 3, m = id & 7;
  const int pr = order[n >> 2], sb4 = n & 3;
  const int e  = ridx[pr];

  const int tid = threadIdx.x;
  const int wid = tid >> 6, lane = tid & 63;
  const int l15 = lane & 15, l16 = lane >> 4;
  const int wm = wid >> 1, wn = wid & 1;

  const char* aSrc = (const char*)(w1t + ((size_t)((e * 8 + m) * 16)) * 8192);
  const char* bSrc = (const char*)(xbf + ((size_t)(n * 16)) * 8192);

  f32x4 acc[4][4];
  #pragma unroll
  for (int i = 0; i < 4; ++i)
    #pragma unroll
    for (int j = 0; j < 4; ++j) acc[i][j] = (f32x4){0.f, 0.f, 0.f, 0.f};

  for (int kb = 0; kb < 16; ++kb) {
    // stage both 16 KB tiles (linear dest; source pre-swizzled)
    #pragma unroll
    for (int i = 0; i < 4; ++i) {
      gload_lds16(aSrc + (size_t)kb * 16384 + i * 4096 + tid * 16,
                  (char*)lA + i * 4096 + tid * 16);
      gload_lds16(bSrc + (size_t)kb * 16384 + i * 4096 + tid * 16,
                  (char*)lB + i * 4096 + tid * 16);
    }
    __syncthreads();   // compiler drains vmcnt(0): DMA writes visible
    #pragma unroll
    for (int ks = 0; ks < 2; ++ks) {
      const int kc = ks * 32 + l16 * 8;
      bf16x8 af[4], bfr[4];
      #pragma unroll
      for (int i = 0; i < 4; ++i) {
        const int row = wm * 64 + i * 16 + l15;
        af[i] = *reinterpret_cast<const bf16x8*>(&lA[row * 64 + (kc ^ ((row & 7) << 3))]);
      }
      #pragma unroll
      for (int j = 0; j < 4; ++j) {
        const int row = wn * 64 + j * 16 + l15;
        bfr[j] = *reinterpret_cast<const bf16x8*>(&lB[row * 64 + (kc ^ ((row & 7) << 3))]);
      }
      #pragma unroll
      for (int i = 0; i < 4; ++i)
        #pragma unroll
        for (int j = 0; j < 4; ++j)
          acc[i][j] = __builtin_amdgcn_mfma_f32_16x16x32_bf16(af[i], bfr[j], acc[i][j], 0, 0, 0);
    }
    __syncthreads();   // reads done before next iteration's DMA overwrites
  }

  // epilogue: + bias, ReLU, sum over the block's 128 s, store partial
  const float* biasE = exp_b1 + e * H_ + m * 128;
  #pragma unroll
  for (int i = 0; i < 4; ++i) {
    #pragma unroll
    for (int r = 0; r < 4; ++r) {
      const int hl = wm * 64 + i * 16 + l16 * 4 + r;   // D row = (lane>>4)*4 + reg
      const float bias = biasE[hl];
      float v = 0.f;
      #pragma unroll
      for (int j = 0; j < 4; ++j) v += fmaxf(acc[i][j][r] + bias, 0.f);
      v += __shfl_xor(v, 1); v += __shfl_xor(v, 2);
      v += __shfl_xor(v, 4); v += __shfl_xor(v, 8);    // reduce 16 s-cols
      if (l15 == 0) sred[wn][hl] = v;
    }
  }
  __syncthreads();
  if (tid < 128) {
    const float val = sred[0][tid] + sred[1][tid];
    ppart[((size_t)sb4 * NPAIR + pr) * H_ + m * 128 + tid] = val;
  }
}

// ---------------------------------------------------------------------------
// Kernel 5: out[b][c] = sum_k rw * ( (sum_sb4 ppart)/S @ W2[e] + b2[e] )
__global__ void finalize_kernel(const float* __restrict__ p_part,
                                const int* __restrict__ ridx, const float* __restrict__ rwgt,
                                const float* __restrict__ w2, const float* __restrict__ b2,
                                float* __restrict__ out) {
  const int b = blockIdx.x, t = threadIdx.x;
  const int c = t & 15, g = t >> 4;
  __shared__ float red[16][17];
  float res = 0.f;
  for (int kk = 0; kk < 2; ++kk) {
    const int pr = b * 2 + kk;
    const int e = ridx[pr];
    const float w = rwgt[pr];
    float dot = 0.f;
    for (int h = g; h < H_; h += 16) {
      float pm = 0.f;
      #pragma unroll
      for (int sb = 0; sb < 4; ++sb) pm += p_part[(size_t)(sb * NPAIR + pr) * H_ + h];
      dot += pm * w2[((size_t)e * H_ + h) * C_ + c];
    }
    red[g][c] = dot;
    __syncthreads();
    if (g == 0) {
      float s = 0.f;
      #pragma unroll
      for (int i = 0; i < 16; ++i) s += red[i][c];
      res += w * (s * (1.f / (float)S_) + b2[e * C_ + c]);
    }
    __syncthreads();
  }
  if (g == 0) out[b * C_ + c] = res;
}

// ---------------------------------------------------------------------------
extern "C" void kernel_launch(void* const* d_in, const int* in_sizes, int n_in,
                              void* d_out, int out_size, void* d_ws, size_t ws_size,
                              hipStream_t stream) {
  const int*   x    = (const int*)  d_in[0];
  const float* emb  = (const float*)d_in[1];
  const float* gw1  = (const float*)d_in[2];
  const float* gb1  = (const float*)d_in[3];
  const float* gw2  = (const float*)d_in[4];
  const float* gb2  = (const float*)d_in[5];
  const float* eemb = (const float*)d_in[6];
  const float* ew1  = (const float*)d_in[7];
  const float* eb1  = (const float*)d_in[8];
  const float* ew2  = (const float*)d_in[9];
  const float* eb2  = (const float*)d_in[10];
  float* out = (float*)d_out;

  char* ws = (char*)d_ws;
  const size_t OFF_W1T   = 0;                              // 16 MiB
  const size_t OFF_XBF   = (size_t)16 << 20;               // 128 MiB
  const size_t OFF_PART  = (size_t)144 << 20;              // 2 MiB
  const size_t OFF_RIDX  = OFF_PART + ((size_t)2 << 20);
  const size_t OFF_RWGT  = OFF_RIDX + 1024;
  const size_t OFF_ORDER = OFF_RWGT + 1024;
  const size_t OFF_PPART = OFF_ORDER + 1024;               // 2 MiB

  ushort* w1t    = (ushort*)(ws + OFF_W1T);
  ushort* xbf    = (ushort*)(ws + OFF_XBF);
  float*  part   = (float*) (ws + OFF_PART);
  int*    ridx   = (int*)   (ws + OFF_RIDX);
  float*  rwgt   = (float*) (ws + OFF_RWGT);
  int*    order  = (int*)   (ws + OFF_ORDER);
  float*  ppart  = (float*) (ws + OFF_PPART);

  prep_kernel<<<dim3(2560), 256, 0, stream>>>(ew1, w1t, x, emb, part);
  gate_kernel<<<dim3(B_), 256, 0, stream>>>(part, gw1, gb1, gw2, gb2, ridx, rwgt);
  sort_pairs_kernel<<<dim3(1), 128, 0, stream>>>(ridx, order);
  gatherconv_kernel<<<dim3(128, 4), 256, 0, stream>>>(x, eemb, ridx, order, xbf);
  gemm_kernel<<<dim3(4096), 256, 0, stream>>>(w1t, xbf, eb1, ridx, order, ppart);
  finalize_kernel<<<dim3(B_), 256, 0, stream>>>(ppart, ridx, rwgt, ew2, eb2, out);
}